// Round 1
// 242.929 us; speedup vs baseline: 1.1626x; 1.1626x over previous
//
#include <hip/hip_runtime.h>
#include <hip/hip_bf16.h>
#include <stdint.h>

// GORU fused cell. B=8192, IN=1024, D=1024, CAP=10.
// 3 launches:
//   prep_all : xs[8192][2048] bf16 = [bf16(x)|bf16(state)];
//              Wt0[1024][1024]=U_c^T; Wt12i[2048][2048] row-INTERLEAVED:
//                row 2c   = [U_r^T|W_r^T] row c  (r-col c)
//                row 2c+1 = [U_g^T|W_g^T] row c  (g-col c)
//              v1/v2[10][1024] butterfly tables
//   gemm     : 256 blocks (1/CU), 512 thr / 8 waves, 8-phase counted-vmcnt
//              pipeline (m201 template). Per block:
//                loop 1: rg 256x256 tile, K=2048 (interleaved cols -> P[.,1024+ct])
//                loop 2: Ucx 256x128 tile, K=1024 (-> P[.,0..1023])
//              Perfect load balance: every block does 8.59e10/256 FLOP.
//   fuse     : out = g*state + (1-g)*modReLU(r*butterfly(state) + Ucx)   [unchanged]

typedef __bf16 bf16x8 __attribute__((ext_vector_type(8)));
typedef __bf16 bf16x4 __attribute__((ext_vector_type(4)));
typedef __bf16 bf16x2 __attribute__((ext_vector_type(2)));
typedef float f32x4 __attribute__((ext_vector_type(4)));

#define B_ROWS 8192

__device__ __forceinline__ void async16(__bf16* lds, const __hip_bfloat16* g) {
    __builtin_amdgcn_global_load_lds((const __attribute__((address_space(1))) void*)g,
                                     (__attribute__((address_space(3))) void*)lds,
                                     16, 0, 0);
}

// ---------------- prep_all: blockIdx-partitioned (xs cast | weight transpose | tables) ----------------
__global__ __launch_bounds__(256) void prep_all(const float* __restrict__ x,
                                                const float* __restrict__ state,
                                                const float* __restrict__ theta,
                                                const float* __restrict__ U,
                                                const float* __restrict__ Wr,
                                                const float* __restrict__ Wg,
                                                __hip_bfloat16* __restrict__ xs,
                                                __hip_bfloat16* __restrict__ Wt0,
                                                __hip_bfloat16* __restrict__ Wt12,
                                                float* __restrict__ v1,
                                                float* __restrict__ v2) {
    __shared__ float tile[32][33];
    const int id = blockIdx.x;
    if (id < 8192) {
        // --- xs = [bf16(x) | bf16(state)] ---
        const int row = id;
        const int col = threadIdx.x * 8;  // 0..2040
        const float* src = (col < 1024) ? (x + (size_t)row * 1024 + col)
                                        : (state + (size_t)row * 1024 + (col - 1024));
        float4 a = *(const float4*)src;
        float4 b = *(const float4*)(src + 4);
        bf16x8 v;
        v[0] = (__bf16)a.x; v[1] = (__bf16)a.y; v[2] = (__bf16)a.z; v[3] = (__bf16)a.w;
        v[4] = (__bf16)b.x; v[5] = (__bf16)b.y; v[6] = (__bf16)b.z; v[7] = (__bf16)b.w;
        *(bf16x8*)((__bf16*)xs + (size_t)row * 2048 + col) = v;
    } else if (id < 13312) {
        // --- weight transpose+cast; Wt12 rows interleaved (r,g) ---
        const int wid = id - 8192;
        const float* src; int srcN, scol, sk;
        __hip_bfloat16* dst; int dstStride, dn, dk;
        bool ilv;
        if (wid < 1024) {
            int nx = wid & 31, ky = wid >> 5;
            src = U; srcN = 3072; scol = nx * 32; sk = ky * 32;
            dst = Wt0; dstStride = 1024; dn = nx * 32; dk = ky * 32;
            ilv = false;
        } else {
            int id2 = wid - 1024;
            int nx = id2 & 63, ky = id2 >> 6;
            int n0 = nx * 32, k0 = ky * 32;
            dst = Wt12; dstStride = 2048; dn = n0; dk = k0;
            ilv = true;
            if (k0 < 1024)      { src = U;  srcN = 3072; scol = 1024 + n0; sk = k0; }
            else if (n0 < 1024) { src = Wr; srcN = 1024; scol = n0;        sk = k0 - 1024; }
            else                { src = Wg; srcN = 1024; scol = n0 - 1024; sk = k0 - 1024; }
        }
        const int tx = threadIdx.x & 31, ty = threadIdx.x >> 5;
#pragma unroll
        for (int s = 0; s < 4; ++s)
            tile[ty + s * 8][tx] = src[(size_t)(sk + ty + s * 8) * srcN + scol + tx];
        __syncthreads();
#pragma unroll
        for (int s = 0; s < 4; ++s) {
            int n = dn + ty + s * 8;
            int wrow = ilv ? ((n < 1024) ? 2 * n : 2 * (n - 1024) + 1) : n;
            dst[(size_t)wrow * dstStride + dk + tx] = __float2bfloat16(tile[tx][ty + s * 8]);
        }
    } else {
        // --- butterfly tables ---
        int idx = (id - 13312) * 256 + threadIdx.x;  // 10240 total
        int i = idx >> 10;
        int j = idx & 1023;
        int Q = 1024 >> i;
        int j0 = j / Q;
        int m = j & (Q - 1);
        int q = (m << i) + j0;
        float th = theta[i * 512 + (q & 511)];
        float c = cosf(th);
        float s = sinf(th);
        v1[idx] = c;
        v2[idx] = (q < 512) ? s : -s;
    }
}

// ---------------- GEMM: 256 blocks, 8-phase 256x256 pipeline ----------------
// LDS layout: [256 rows][8 chunks of 16B], physical chunk = logical ^ (row&7).
// Stage writes linear (global source pre-inverse-swizzled); reads apply the XOR.
// Frag conventions (verified by predecessor kernel):
//   a-frag: A row (Moff + r0), k-chunk gq (+32 elem for kk=1)
//   b-frag: B row (Noff + r0), same chunks
//   D[lane][reg] = C[Moff + gq*4 + reg][Noff + r0]
#define BAR()   asm volatile("s_barrier" ::: "memory")
#define LGKM0() asm volatile("s_waitcnt lgkmcnt(0)" ::: "memory")
#define LGKM8() asm volatile("s_waitcnt lgkmcnt(8)" ::: "memory")
#define VMCNT(n) asm volatile("s_waitcnt vmcnt(" #n ")" ::: "memory")

__global__ __launch_bounds__(512, 2) void gemm_fused(const __hip_bfloat16* __restrict__ xs,
                                                     const __hip_bfloat16* __restrict__ Wt0,
                                                     const __hip_bfloat16* __restrict__ Wt12,
                                                     const float* __restrict__ bias_r,
                                                     const float* __restrict__ bias_g,
                                                     __hip_bfloat16* __restrict__ P) {
    __shared__ __align__(16) __bf16 As[2][16384];   // 2 x 256x64
    __shared__ __align__(16) __bf16 Bs[2][16384];   // 2 x 256x64 (Ucx uses rows 0..127)

    // bijective XCD swizzle: 256 blocks, 32 consecutive tiles per XCD
    const int bid = blockIdx.x;
    const int swz = (bid & 7) * 32 + (bid >> 3);
    const int nt = swz & 7;         // col tile (rg: 256 interleaved cols; ucx: 128 cols)
    const int mt = swz >> 3;        // row tile
    const int mBase = mt * 256;

    const int t = threadIdx.x;      // 0..511
    const int lane = t & 63;
    const int wv = t >> 6;          // 0..7
    const int wm = wv & 1;          // M half (128 rows)
    const int wn = wv >> 1;         // N quarter
    const int r0 = lane & 15;
    const int gq = lane >> 4;

    // ds_read swizzled chunk offsets (elements within a 64-elem row)
    const int coff0 = ((gq ^ (r0 & 7)) << 3);
    const int coff1 = coff0 ^ 32;
    const int rowA = wm * 128 + r0;
    const int rowB = wn * 64 + r0;
    const int rowBu = wn * 32 + r0;

    // staging constants: thread t stages chunk (row=t>>3, phys=t&7) of each half-tile
    const int s_row = t >> 3;                          // 0..63
    const int s_q8 = (((t & 7) ^ (s_row & 7)) << 3);   // pre-inverse-swizzled source chunk

    const __hip_bfloat16* Ag = xs + (size_t)(mBase + s_row) * 2048 + s_q8;
    const __hip_bfloat16* Bg = Wt12 + (size_t)(nt * 256 + s_row) * 2048 + s_q8;
    const __hip_bfloat16* Cg = Wt0 + (size_t)(nt * 128 + s_row) * 1024 + s_q8;

#define STG_A(buf, h, kt) do { \
    async16(&As[buf][(((h) << 10) + t) << 3],       Ag + (size_t)((h) * 128) * 2048 + (kt) * 64); \
    async16(&As[buf][(((h) << 10) + 512 + t) << 3], Ag + (size_t)((h) * 128 + 64) * 2048 + (kt) * 64); \
} while (0)
#define STG_B(buf, h, kt) do { \
    async16(&Bs[buf][(((h) << 10) + t) << 3],       Bg + (size_t)((h) * 128) * 2048 + (kt) * 64); \
    async16(&Bs[buf][(((h) << 10) + 512 + t) << 3], Bg + (size_t)((h) * 128 + 64) * 2048 + (kt) * 64); \
} while (0)
#define STG_C(buf, kt) do { \
    async16(&Bs[buf][t << 3],         Cg + (kt) * 64); \
    async16(&Bs[buf][(512 + t) << 3], Cg + (size_t)64 * 1024 + (kt) * 64); \
} while (0)

#define LOAD_AFL(bufArr) do { _Pragma("unroll") for (int i = 0; i < 4; ++i) { \
    afl[i][0] = *(const bf16x8*)&bufArr[(rowA + i * 16) * 64 + coff0]; \
    afl[i][1] = *(const bf16x8*)&bufArr[(rowA + i * 16) * 64 + coff1]; } } while (0)
#define LOAD_AFH(bufArr) do { _Pragma("unroll") for (int i = 0; i < 4; ++i) { \
    afh[i][0] = *(const bf16x8*)&bufArr[(rowA + 64 + i * 16) * 64 + coff0]; \
    afh[i][1] = *(const bf16x8*)&bufArr[(rowA + 64 + i * 16) * 64 + coff1]; } } while (0)
#define LOAD_BB(bufArr, base) do { _Pragma("unroll") for (int j = 0; j < 2; ++j) { \
    bb[j][0] = *(const bf16x8*)&bufArr[((base) + j * 16) * 64 + coff0]; \
    bb[j][1] = *(const bf16x8*)&bufArr[((base) + j * 16) * 64 + coff1]; } } while (0)
#define MFMA8(I0, J0, af) do { _Pragma("unroll") for (int i = 0; i < 4; ++i) \
    _Pragma("unroll") for (int j = 0; j < 2; ++j) { \
    acc[(I0) + i][(J0) + j] = __builtin_amdgcn_mfma_f32_16x16x32_bf16(af[i][0], bb[j][0], acc[(I0) + i][(J0) + j], 0, 0, 0); \
    acc[(I0) + i][(J0) + j] = __builtin_amdgcn_mfma_f32_16x16x32_bf16(af[i][1], bb[j][1], acc[(I0) + i][(J0) + j], 0, 0, 0); } } while (0)

    f32x4 acc[8][4];
    bf16x8 afl[4][2], afh[4][2], bb[2][2];
    const f32x4 zero = {0.f, 0.f, 0.f, 0.f};
#pragma unroll
    for (int i = 0; i < 8; ++i)
#pragma unroll
        for (int j = 0; j < 4; ++j) acc[i][j] = zero;

    // ======== rg loop: 256x256, K=2048, 32 K-tiles of 64, 16 iterations x 8 phases ========
    // prologue: tile0 complete + tile1 A-halves in flight
    STG_A(0, 0, 0); STG_A(0, 1, 0);
    STG_B(0, 0, 0); STG_B(0, 1, 0);
    STG_A(1, 0, 1); STG_A(1, 1, 1);
    VMCNT(4);
    BAR();

#pragma unroll 1
    for (int u = 0; u < 16; ++u) {
        const int kt1 = 2 * u + 1;
        const int kt2 = (2 * u + 2) & 31;
        const int kt3 = (2 * u + 3) & 31;

        // P1: tile kt (buf0) Q(i0-3 x j0-1); stage B(kt+1)h0 -> buf1
        LOAD_AFL(As[0]);
        LOAD_BB(Bs[0], rowB);
        STG_B(1, 0, kt1);
        LGKM8();
        BAR(); LGKM0();
        __builtin_amdgcn_s_setprio(1); MFMA8(0, 0, afl); __builtin_amdgcn_s_setprio(0);
        BAR();
        // P2: Q(i4-7 x j0-1); stage B(kt+1)h1 -> buf1
        LOAD_AFH(As[0]);
        STG_B(1, 1, kt1);
        BAR(); LGKM0();
        __builtin_amdgcn_s_setprio(1); MFMA8(4, 0, afh); __builtin_amdgcn_s_setprio(0);
        BAR();
        // P3: Q(i0-3 x j2-3); stage A(kt+2)h0 -> buf0 (buf0-A last read in P2)
        LOAD_BB(Bs[0], rowB + 32);
        STG_A(0, 0, kt2);
        BAR(); LGKM0();
        __builtin_amdgcn_s_setprio(1); MFMA8(0, 2, afl); __builtin_amdgcn_s_setprio(0);
        BAR();
        // P4: Q(i4-7 x j2-3); stage A(kt+2)h1; gate buf1 (tile kt+1) readiness
        STG_A(0, 1, kt2);
        BAR();
        __builtin_amdgcn_s_setprio(1); MFMA8(4, 2, afh); __builtin_amdgcn_s_setprio(0);
        VMCNT(4);
        BAR();
        // P5: tile kt+1 (buf1) Q(i0-3 x j0-1); stage B(kt+2)h0 -> buf0 (last read P3)
        LOAD_AFL(As[1]);
        LOAD_BB(Bs[1], rowB);
        STG_B(0, 0, kt2);
        LGKM8();
        BAR(); LGKM0();
        __builtin_amdgcn_s_setprio(1); MFMA8(0, 0, afl); __builtin_amdgcn_s_setprio(0);
        BAR();
        // P6: Q(i4-7 x j0-1); stage B(kt+2)h1 -> buf0
        LOAD_AFH(As[1]);
        STG_B(0, 1, kt2);
        BAR(); LGKM0();
        __builtin_amdgcn_s_setprio(1); MFMA8(4, 0, afh); __builtin_amdgcn_s_setprio(0);
        BAR();
        // P7: Q(i0-3 x j2-3); stage A(kt+3)h0 -> buf1 (buf1-A last read P6)
        LOAD_BB(Bs[1], rowB + 32);
        STG_A(1, 0, kt3);
        BAR(); LGKM0();
        __builtin_amdgcn_s_setprio(1); MFMA8(0, 2, afl); __builtin_amdgcn_s_setprio(0);
        BAR();
        // P8: Q(i4-7 x j2-3); stage A(kt+3)h1; gate buf0 (tile kt+2) readiness
        STG_A(1, 1, kt3);
        BAR();
        __builtin_amdgcn_s_setprio(1); MFMA8(4, 2, afh); __builtin_amdgcn_s_setprio(0);
        VMCNT(4);
        BAR();
    }

    // drain stale prefetches before reusing LDS for the Ucx loop
    VMCNT(0);
    BAR();

    // Ucx prologue: issue now, land under the rg epilogue
    STG_A(0, 0, 0); STG_A(0, 1, 0);
    STG_C(0, 0);
    STG_C(1, 1);

    // ======== rg epilogue: sigmoid(+bias), P cols [1024, 3072) (interleaved r,g) ========
#pragma unroll
    for (int j = 0; j < 4; ++j) {
        const int ct = nt * 256 + wn * 64 + j * 16 + r0;   // interleaved col, parity = r0&1
        const float bias = (r0 & 1) ? bias_g[ct >> 1] : bias_r[ct >> 1];
#pragma unroll
        for (int i = 0; i < 8; ++i) {
#pragma unroll
            for (int reg = 0; reg < 4; ++reg) {
                const int row = mBase + wm * 128 + i * 16 + gq * 4 + reg;
                const float z = 1.0f / (1.0f + __expf(-(acc[i][j][reg] + bias)));
                P[(size_t)row * 3072 + 1024 + ct] = __float2bfloat16(z);
            }
        }
    }

    VMCNT(0);
    BAR();

    // ======== Ucx loop: 256x128, K=1024, 16 K-tiles, 8 iterations x 4 phases ========
#pragma unroll
    for (int i = 0; i < 8; ++i)
#pragma unroll
        for (int j = 0; j < 2; ++j) acc[i][j] = zero;

#pragma unroll 1
    for (int u = 0; u < 8; ++u) {
        const int kt1 = 2 * u + 1;
        const int kt2 = (2 * u + 2) & 15;
        const int kt3 = (2 * u + 3) & 15;

        // P1: tile kt (buf0): i0-3; stage A(kt+1) -> buf1 (buf1-A last read prev P4)
        LOAD_AFL(As[0]);
        LOAD_BB(Bs[0], rowBu);
        STG_A(1, 0, kt1); STG_A(1, 1, kt1);
        LGKM8();
        BAR(); LGKM0();
        __builtin_amdgcn_s_setprio(1); MFMA8(0, 0, afl); __builtin_amdgcn_s_setprio(0);
        BAR();
        // P2: i4-7; stage C(kt+2) -> buf0-B (last read P1); gate tile kt+1
        LOAD_AFH(As[0]);
        STG_C(0, kt2);
        BAR(); LGKM0();
        __builtin_amdgcn_s_setprio(1); MFMA8(4, 0, afh); __builtin_amdgcn_s_setprio(0);
        VMCNT(2);
        BAR();
        // P3: tile kt+1 (buf1): i0-3; stage A(kt+2) -> buf0-A (last read P2)
        LOAD_AFL(As[1]);
        LOAD_BB(Bs[1], rowBu);
        STG_A(0, 0, kt2); STG_A(0, 1, kt2);
        LGKM8();
        BAR(); LGKM0();
        __builtin_amdgcn_s_setprio(1); MFMA8(0, 0, afl); __builtin_amdgcn_s_setprio(0);
        BAR();
        // P4: i4-7; stage C(kt+3) -> buf1-B (last read P3); gate tile kt+2
        LOAD_AFH(As[1]);
        STG_C(1, kt3);
        BAR(); LGKM0();
        __builtin_amdgcn_s_setprio(1); MFMA8(4, 0, afh); __builtin_amdgcn_s_setprio(0);
        VMCNT(2);
        BAR();
    }

    // ======== Ucx epilogue: raw bf16, P cols [0, 1024) ========
#pragma unroll
    for (int j = 0; j < 2; ++j) {
        const int col = nt * 128 + wn * 32 + j * 16 + r0;
#pragma unroll
        for (int i = 0; i < 8; ++i) {
#pragma unroll
            for (int reg = 0; reg < 4; ++reg) {
                const int row = mBase + wm * 128 + i * 16 + gq * 4 + reg;
                P[(size_t)row * 3072 + col] = __float2bfloat16(acc[i][j][reg]);
            }
        }
    }
    VMCNT(0);
}

#undef STG_A
#undef STG_B
#undef STG_C
#undef LOAD_AFL
#undef LOAD_AFH
#undef LOAD_BB
#undef MFMA8

// ---------------- fused butterfly + modReLU + gate ----------------
// Thread t owns cols 4t..4t+3 of 8 rows (all registers).
// Stage H=512: LDS partner t^128; H=256: LDS partner t^64 (3 barriers total).
// Stages H=128..4: __shfl_xor lanemask H/4. Stages H=2,1: in-register permute.
__global__ __launch_bounds__(256) void fuse_kernel(const float* __restrict__ state,
                                                   const __hip_bfloat16* __restrict__ P,
                                                   const float* __restrict__ v1,
                                                   const float* __restrict__ v2,
                                                   const float* __restrict__ bias_c,
                                                   float* __restrict__ out) {
    __shared__ float hbuf[8][1024];
    const int t = threadIdx.x;
    const int rowBase = blockIdx.x * 8;

    float h[8][4];
    float sv[8][4];
#pragma unroll
    for (int r = 0; r < 8; ++r) {
        float4 s4 = ((const float4*)(state + (size_t)(rowBase + r) * 1024))[t];
        h[r][0] = s4.x; h[r][1] = s4.y; h[r][2] = s4.z; h[r][3] = s4.w;
        sv[r][0] = s4.x; sv[r][1] = s4.y; sv[r][2] = s4.z; sv[r][3] = s4.w;
        *(float4*)&hbuf[r][4 * t] = s4;
    }

    // stage 0: H=512, partner thread t^128 (cross-wave -> LDS)
    {
        __syncthreads();
        float4 w1 = *(const float4*)&v1[4 * t];
        float4 w2 = *(const float4*)&v2[4 * (t ^ 128)];
        const float w1v[4] = {w1.x, w1.y, w1.z, w1.w};
        const float w2v[4] = {w2.x, w2.y, w2.z, w2.w};
#pragma unroll
        for (int r = 0; r < 8; ++r) {
            float4 pr = *(const float4*)&hbuf[r][4 * (t ^ 128)];
            const float pv[4] = {pr.x, pr.y, pr.z, pr.w};
#pragma unroll
            for (int e = 0; e < 4; ++e) h[r][e] = h[r][e] * w1v[e] + pv[e] * w2v[e];
        }
        __syncthreads();  // stage-0 reads done before stage-1 writes
    }
    // stage 1: H=256, partner thread t^64 (cross-wave -> LDS)
    {
#pragma unroll
        for (int r = 0; r < 8; ++r)
            *(float4*)&hbuf[r][4 * t] = (float4){h[r][0], h[r][1], h[r][2], h[r][3]};
        __syncthreads();
        float4 w1 = *(const float4*)&v1[1024 + 4 * t];
        float4 w2 = *(const float4*)&v2[1024 + 4 * (t ^ 64)];
        const float w1v[4] = {w1.x, w1.y, w1.z, w1.w};
        const float w2v[4] = {w2.x, w2.y, w2.z, w2.w};
#pragma unroll
        for (int r = 0; r < 8; ++r) {
            float4 pr = *(const float4*)&hbuf[r][4 * (t ^ 64)];
            const float pv[4] = {pr.x, pr.y, pr.z, pr.w};
#pragma unroll
            for (int e = 0; e < 4; ++e) h[r][e] = h[r][e] * w1v[e] + pv[e] * w2v[e];
        }
    }
    // stages 2..7: H=128..4, in-wave shfl_xor with lanemask H/4
#pragma unroll
    for (int i = 2; i <= 7; ++i) {
        const int H = 512 >> i;
        const int lm = H >> 2;  // 32,16,8,4,2,1
        float4 w1 = *(const float4*)&v1[i * 1024 + 4 * t];
        float4 w2 = *(const float4*)&v2[i * 1024 + 4 * (t ^ lm)];
        const float w1v[4] = {w1.x, w1.y, w1.z, w1.w};
        const float w2v[4] = {w2.x, w2.y, w2.z, w2.w};
#pragma unroll
        for (int r = 0; r < 8; ++r) {
#pragma unroll
            for (int e = 0; e < 4; ++e) {
                float p = __shfl_xor(h[r][e], lm, 64);
                h[r][e] = h[r][e] * w1v[e] + p * w2v[e];
            }
        }
    }
    // stage 8: H=2 (element permute e^2); stage 9: H=1 (e^1)
    {
        float4 w1 = *(const float4*)&v1[8 * 1024 + 4 * t];
        float4 w2 = *(const float4*)&v2[8 * 1024 + 4 * t];
        const float w1v[4] = {w1.x, w1.y, w1.z, w1.w};
        const float w2v[4] = {w2.x, w2.y, w2.z, w2.w};
#pragma unroll
        for (int r = 0; r < 8; ++r) {
            float nh[4];
#pragma unroll
            for (int e = 0; e < 4; ++e) nh[e] = h[r][e] * w1v[e] + h[r][e ^ 2] * w2v[e ^ 2];
#pragma unroll
            for (int e = 0; e < 4; ++e) h[r][e] = nh[e];
        }
        float4 u1 = *(const float4*)&v1[9 * 1024 + 4 * t];
        float4 u2 = *(const float4*)&v2[9 * 1024 + 4 * t];
        const float u1v[4] = {u1.x, u1.y, u1.z, u1.w};
        const float u2v[4] = {u2.x, u2.y, u2.z, u2.w};
#pragma unroll
        for (int r = 0; r < 8; ++r) {
            float nh[4];
#pragma unroll
            for (int e = 0; e < 4; ++e) nh[e] = h[r][e] * u1v[e] + h[r][e ^ 1] * u2v[e ^ 1];
#pragma unroll
            for (int e = 0; e < 4; ++e) h[r][e] = nh[e];
        }
    }

    // epilogue: modReLU + gate
    const float4 bc = ((const float4*)bias_c)[t];
    const float bcv[4] = {bc.x, bc.y, bc.z, bc.w};
#pragma unroll
    for (int r = 0; r < 8; ++r) {
        const int row = rowBase + r;
        const __hip_bfloat16* Pr = P + (size_t)row * 3072;
        bf16x4 ux = *(const bf16x4*)((const __bf16*)Pr + 4 * t);        // Ucx, 8 B
        bf16x8 rg = *(const bf16x8*)((const __bf16*)Pr + 1024 + 8 * t); // (r,g) pairs, 16 B
        float o[4];
#pragma unroll
        for (int e = 0; e < 4; ++e) {
            float Ucx = (float)ux[e];
            float rr  = (float)rg[2 * e];
            float gg  = (float)rg[2 * e + 1];
            float pre = rr * h[r][e] + Ucx;
            float mag = fabsf(pre) + 0.001f + bcv[e];
            float c = (pre > 0.f) ? mag : ((pre < 0.f) ? -mag : 0.f);
            o[e] = gg * sv[r][e] + (1.f - gg) * c;
        }
        ((float4*)(out + (size_t)row * 1024))[t] = (float4){o[0], o[1], o[2], o[3]};
    }
}

extern "C" void kernel_launch(void* const* d_in, const int* in_sizes, int n_in,
                              void* d_out, int out_size, void* d_ws, size_t ws_size,
                              hipStream_t stream) {
    const float* x      = (const float*)d_in[0];
    const float* state  = (const float*)d_in[1];
    const float* theta  = (const float*)d_in[2];
    const float* U      = (const float*)d_in[3];
    const float* W_r    = (const float*)d_in[4];
    const float* W_g    = (const float*)d_in[5];
    const float* bias_r = (const float*)d_in[6];
    const float* bias_g = (const float*)d_in[7];
    const float* bias_c = (const float*)d_in[8];
    float* out = (float*)d_out;

    // workspace layout (~90.1 MB)
    __hip_bfloat16* xs   = (__hip_bfloat16*)d_ws;                      // 32 MB
    __hip_bfloat16* Wt0  = xs + (size_t)B_ROWS * 2048;                 // 2 MB
    __hip_bfloat16* Wt12 = Wt0 + (size_t)1024 * 1024;                  // 8 MB (row-interleaved r,g)
    __hip_bfloat16* P    = Wt12 + (size_t)2048 * 2048;                 // 48 MB
    float* v1 = (float*)(P + (size_t)B_ROWS * 3072);                   // 40 KB
    float* v2 = v1 + 10 * 1024;                                        // 40 KB

    prep_all<<<13352, 256, 0, stream>>>(x, state, theta, U, W_r, W_g, xs, Wt0, Wt12, v1, v2);
    gemm_fused<<<256, 512, 0, stream>>>(xs, Wt0, Wt12, bias_r, bias_g, P);
    fuse_kernel<<<1024, 256, 0, stream>>>(state, P, v1, v2, bias_c, out);
}

// Round 2
// 242.849 us; speedup vs baseline: 1.1630x; 1.0003x over previous
//
#include <hip/hip_runtime.h>
#include <hip/hip_bf16.h>
#include <stdint.h>

// GORU fused cell. B=8192, IN=1024, D=1024, CAP=10.
// 3 launches:
//   prep_all : xs[8192][2048] bf16 = [bf16(x)|bf16(state)];
//              Wt0[1024][1024]=U_c^T; Wt12i[2048][2048] row-INTERLEAVED (r,g)
//              v1/v2[10][1024] butterfly tables
//   gemm     : 256 blocks (1/CU), 512 thr / 8 waves, 8-phase counted-vmcnt
//              pipeline with ONE-PHASE ds_read LOOKAHEAD (reads for phase p
//              issued during phase p-1's MFMA; gates moved to P3/P7 so the
//              next tile's first frags issue at P4/P8). Counted lgkmcnt.
//   fuse     : out = g*state + (1-g)*modReLU(r*butterfly(state) + Ucx)

typedef __bf16 bf16x8 __attribute__((ext_vector_type(8)));
typedef __bf16 bf16x4 __attribute__((ext_vector_type(4)));
typedef __bf16 bf16x2 __attribute__((ext_vector_type(2)));
typedef float f32x4 __attribute__((ext_vector_type(4)));

#define B_ROWS 8192

__device__ __forceinline__ void async16(__bf16* lds, const __hip_bfloat16* g) {
    __builtin_amdgcn_global_load_lds((const __attribute__((address_space(1))) void*)g,
                                     (__attribute__((address_space(3))) void*)lds,
                                     16, 0, 0);
}

// ---------------- prep_all: blockIdx-partitioned (xs cast | weight transpose | tables) ----------------
__global__ __launch_bounds__(256) void prep_all(const float* __restrict__ x,
                                                const float* __restrict__ state,
                                                const float* __restrict__ theta,
                                                const float* __restrict__ U,
                                                const float* __restrict__ Wr,
                                                const float* __restrict__ Wg,
                                                __hip_bfloat16* __restrict__ xs,
                                                __hip_bfloat16* __restrict__ Wt0,
                                                __hip_bfloat16* __restrict__ Wt12,
                                                float* __restrict__ v1,
                                                float* __restrict__ v2) {
    __shared__ float tile[32][33];
    const int id = blockIdx.x;
    if (id < 8192) {
        // --- xs = [bf16(x) | bf16(state)] ---
        const int row = id;
        const int col = threadIdx.x * 8;  // 0..2040
        const float* src = (col < 1024) ? (x + (size_t)row * 1024 + col)
                                        : (state + (size_t)row * 1024 + (col - 1024));
        float4 a = *(const float4*)src;
        float4 b = *(const float4*)(src + 4);
        bf16x8 v;
        v[0] = (__bf16)a.x; v[1] = (__bf16)a.y; v[2] = (__bf16)a.z; v[3] = (__bf16)a.w;
        v[4] = (__bf16)b.x; v[5] = (__bf16)b.y; v[6] = (__bf16)b.z; v[7] = (__bf16)b.w;
        *(bf16x8*)((__bf16*)xs + (size_t)row * 2048 + col) = v;
    } else if (id < 13312) {
        // --- weight transpose+cast; Wt12 rows interleaved (r,g) ---
        const int wid = id - 8192;
        const float* src; int srcN, scol, sk;
        __hip_bfloat16* dst; int dstStride, dn, dk;
        bool ilv;
        if (wid < 1024) {
            int nx = wid & 31, ky = wid >> 5;
            src = U; srcN = 3072; scol = nx * 32; sk = ky * 32;
            dst = Wt0; dstStride = 1024; dn = nx * 32; dk = ky * 32;
            ilv = false;
        } else {
            int id2 = wid - 1024;
            int nx = id2 & 63, ky = id2 >> 6;
            int n0 = nx * 32, k0 = ky * 32;
            dst = Wt12; dstStride = 2048; dn = n0; dk = k0;
            ilv = true;
            if (k0 < 1024)      { src = U;  srcN = 3072; scol = 1024 + n0; sk = k0; }
            else if (n0 < 1024) { src = Wr; srcN = 1024; scol = n0;        sk = k0 - 1024; }
            else                { src = Wg; srcN = 1024; scol = n0 - 1024; sk = k0 - 1024; }
        }
        const int tx = threadIdx.x & 31, ty = threadIdx.x >> 5;
#pragma unroll
        for (int s = 0; s < 4; ++s)
            tile[ty + s * 8][tx] = src[(size_t)(sk + ty + s * 8) * srcN + scol + tx];
        __syncthreads();
#pragma unroll
        for (int s = 0; s < 4; ++s) {
            int n = dn + ty + s * 8;
            int wrow = ilv ? ((n < 1024) ? 2 * n : 2 * (n - 1024) + 1) : n;
            dst[(size_t)wrow * dstStride + dk + tx] = __float2bfloat16(tile[tx][ty + s * 8]);
        }
    } else {
        // --- butterfly tables ---
        int idx = (id - 13312) * 256 + threadIdx.x;  // 10240 total
        int i = idx >> 10;
        int j = idx & 1023;
        int Q = 1024 >> i;
        int j0 = j / Q;
        int m = j & (Q - 1);
        int q = (m << i) + j0;
        float th = theta[i * 512 + (q & 511)];
        float c = cosf(th);
        float s = sinf(th);
        v1[idx] = c;
        v2[idx] = (q < 512) ? s : -s;
    }
}

// ---------------- GEMM: 256 blocks, 8-phase 256x256 pipeline with read-lookahead ----------------
// LDS layout: [256 rows][8 chunks of 16B], physical chunk = logical ^ (row&7).
// Stage writes linear (global source pre-inverse-swizzled); reads apply the XOR.
// Read schedule (one phase ahead of consuming MFMA):
//   P8: afl''+bb0'' (buf0, post-G2) | P1: afh | P2: bb1 | P3: - (G1 at end)
//   P4: afl'+bb0' (buf1, post-G1)   | P5: afh'| P6: bb1'| P7: - (G2 at end)
// Region ledger (read confirmed by lgkm+barrier BEFORE its re-stage):
//   afl/bb0 conf P1-lgkm8; afh conf P2-lgkm4; bb1 conf P3-lgkm0;
//   stages: A h0@P3, A h1@P4, B h0@P5, B h1@P6 -- all >=1 phase after confirm.
#define BAR()    asm volatile("s_barrier" ::: "memory")
#define LGKM(n)  asm volatile("s_waitcnt lgkmcnt(" #n ")" ::: "memory")
#define VMCNT(n) asm volatile("s_waitcnt vmcnt(" #n ")" ::: "memory")
#define SCHEDB() __builtin_amdgcn_sched_barrier(0)
#define PRIO1()  __builtin_amdgcn_s_setprio(1)
#define PRIO0()  __builtin_amdgcn_s_setprio(0)

__global__ __launch_bounds__(512, 2) void gemm_fused(const __hip_bfloat16* __restrict__ xs,
                                                     const __hip_bfloat16* __restrict__ Wt0,
                                                     const __hip_bfloat16* __restrict__ Wt12,
                                                     const float* __restrict__ bias_r,
                                                     const float* __restrict__ bias_g,
                                                     __hip_bfloat16* __restrict__ P) {
    __shared__ __align__(16) __bf16 As[2][16384];   // 2 x 256x64
    __shared__ __align__(16) __bf16 Bs[2][16384];   // 2 x 256x64 (Ucx uses rows 0..127)

    // bijective XCD swizzle: 256 blocks, 32 consecutive tiles per XCD
    const int bid = blockIdx.x;
    const int swz = (bid & 7) * 32 + (bid >> 3);
    const int nt = swz & 7;         // col tile (rg: 256 interleaved cols; ucx: 128 cols)
    const int mt = swz >> 3;        // row tile
    const int mBase = mt * 256;

    const int t = threadIdx.x;      // 0..511
    const int lane = t & 63;
    const int wv = t >> 6;          // 0..7
    const int wm = wv & 1;          // M half (128 rows)
    const int wn = wv >> 1;         // N quarter
    const int r0 = lane & 15;
    const int gq = lane >> 4;

    // ds_read swizzled chunk offsets (elements within a 64-elem row)
    const int coff0 = ((gq ^ (r0 & 7)) << 3);
    const int coff1 = coff0 ^ 32;
    const int rowA = wm * 128 + r0;
    const int rowB = wn * 64 + r0;
    const int rowBu = wn * 32 + r0;

    // staging constants: thread t stages chunk (row=t>>3, phys=t&7) of each half-tile
    const int s_row = t >> 3;                          // 0..63
    const int s_q8 = (((t & 7) ^ (s_row & 7)) << 3);   // pre-inverse-swizzled source chunk

    const __hip_bfloat16* Ag = xs + (size_t)(mBase + s_row) * 2048 + s_q8;
    const __hip_bfloat16* Bg = Wt12 + (size_t)(nt * 256 + s_row) * 2048 + s_q8;
    const __hip_bfloat16* Cg = Wt0 + (size_t)(nt * 128 + s_row) * 1024 + s_q8;

#define STG_A(buf, h, kt) do { \
    async16(&As[buf][(((h) << 10) + t) << 3],       Ag + (size_t)((h) * 128) * 2048 + (kt) * 64); \
    async16(&As[buf][(((h) << 10) + 512 + t) << 3], Ag + (size_t)((h) * 128 + 64) * 2048 + (kt) * 64); \
} while (0)
#define STG_B(buf, h, kt) do { \
    async16(&Bs[buf][(((h) << 10) + t) << 3],       Bg + (size_t)((h) * 128) * 2048 + (kt) * 64); \
    async16(&Bs[buf][(((h) << 10) + 512 + t) << 3], Bg + (size_t)((h) * 128 + 64) * 2048 + (kt) * 64); \
} while (0)
#define STG_C(buf, kt) do { \
    async16(&Bs[buf][t << 3],         Cg + (kt) * 64); \
    async16(&Bs[buf][(512 + t) << 3], Cg + (size_t)64 * 1024 + (kt) * 64); \
} while (0)

#define LOAD_AF(dst, bufArr, rbase) do { _Pragma("unroll") for (int i_ = 0; i_ < 4; ++i_) { \
    dst[i_][0] = *(const bf16x8*)&bufArr[((rbase) + i_ * 16) * 64 + coff0]; \
    dst[i_][1] = *(const bf16x8*)&bufArr[((rbase) + i_ * 16) * 64 + coff1]; } } while (0)
#define LOAD_BF(dst, bufArr, rbase) do { _Pragma("unroll") for (int j_ = 0; j_ < 2; ++j_) { \
    dst[j_][0] = *(const bf16x8*)&bufArr[((rbase) + j_ * 16) * 64 + coff0]; \
    dst[j_][1] = *(const bf16x8*)&bufArr[((rbase) + j_ * 16) * 64 + coff1]; } } while (0)
#define MFMA8(I0, J0, af, bf_) do { _Pragma("unroll") for (int i_ = 0; i_ < 4; ++i_) \
    _Pragma("unroll") for (int j_ = 0; j_ < 2; ++j_) { \
    acc[(I0) + i_][(J0) + j_] = __builtin_amdgcn_mfma_f32_16x16x32_bf16(af[i_][0], bf_[j_][0], acc[(I0) + i_][(J0) + j_], 0, 0, 0); \
    acc[(I0) + i_][(J0) + j_] = __builtin_amdgcn_mfma_f32_16x16x32_bf16(af[i_][1], bf_[j_][1], acc[(I0) + i_][(J0) + j_], 0, 0, 0); } } while (0)

    f32x4 acc[8][4];
    bf16x8 afl[4][2], afh[4][2], bb0[2][2], bb1[2][2];
    const f32x4 zero = {0.f, 0.f, 0.f, 0.f};
#pragma unroll
    for (int i = 0; i < 8; ++i)
#pragma unroll
        for (int j = 0; j < 4; ++j) acc[i][j] = zero;

    // ======== rg loop: 256x256, K=2048, 32 K-tiles of 64, 16 iterations x 8 phases ========
    // prologue: tile0 complete + tile1 A-halves in flight; pre-issue tile0's afl+bb0
    STG_A(0, 0, 0); STG_A(0, 1, 0);
    STG_B(0, 0, 0); STG_B(0, 1, 0);
    STG_A(1, 0, 1); STG_A(1, 1, 1);
    VMCNT(4);
    BAR();
    LOAD_AF(afl, As[0], rowA);
    LOAD_BF(bb0, Bs[0], rowB);

#pragma unroll 1
    for (int u = 0; u < 16; ++u) {
        const int kt1 = 2 * u + 1;
        const int kt2 = (2 * u + 2) & 31;
        const int kt3 = (2 * u + 3) & 31;

        // P1: MFMA Q(i0-3,j0-1) on afl/bb0 (issued prev P8); issue afh; stage B(kt+1)h0
        LOAD_AF(afh, As[0], rowA + 64);
        STG_B(1, 0, kt1);
        BAR(); LGKM(8); SCHEDB();
        PRIO1(); MFMA8(0, 0, afl, bb0); PRIO0();
        BAR();
        // P2: Q(i4-7,j0-1); issue bb1; stage B(kt+1)h1
        LOAD_BF(bb1, Bs[0], rowB + 32);
        STG_B(1, 1, kt1);
        BAR(); LGKM(4); SCHEDB();
        PRIO1(); MFMA8(4, 0, afh, bb0); PRIO0();
        BAR();
        // P3: Q(i0-3,j2-3); stage A(kt+2)h0; G1: buf1 (tile kt+1) ready
        STG_A(0, 0, kt2);
        BAR(); LGKM(0); SCHEDB();
        PRIO1(); MFMA8(0, 2, afl, bb1); PRIO0();
        VMCNT(2);
        BAR();
        // P4: Q(i4-7,j2-3); issue afl'/bb0' (buf1, post-gate); stage A(kt+2)h1
        LOAD_AF(afl, As[1], rowA);
        LOAD_BF(bb0, Bs[1], rowB);
        STG_A(0, 1, kt2);
        BAR(); LGKM(12); SCHEDB();
        PRIO1(); MFMA8(4, 2, afh, bb1); PRIO0();
        BAR();
        // P5: tile kt+1 Q(i0-3,j0-1); issue afh'; stage B(kt+2)h0
        LOAD_AF(afh, As[1], rowA + 64);
        STG_B(0, 0, kt2);
        BAR(); LGKM(8); SCHEDB();
        PRIO1(); MFMA8(0, 0, afl, bb0); PRIO0();
        BAR();
        // P6: Q(i4-7,j0-1); issue bb1'; stage B(kt+2)h1
        LOAD_BF(bb1, Bs[1], rowB + 32);
        STG_B(0, 1, kt2);
        BAR(); LGKM(4); SCHEDB();
        PRIO1(); MFMA8(4, 0, afh, bb0); PRIO0();
        BAR();
        // P7: Q(i0-3,j2-3); stage A(kt+3)h0; G2: buf0 (tile kt+2) ready
        STG_A(1, 0, kt3);
        BAR(); LGKM(0); SCHEDB();
        PRIO1(); MFMA8(0, 2, afl, bb1); PRIO0();
        VMCNT(2);
        BAR();
        // P8: Q(i4-7,j2-3); issue afl''/bb0'' (buf0, post-gate); stage A(kt+3)h1
        LOAD_AF(afl, As[0], rowA);
        LOAD_BF(bb0, Bs[0], rowB);
        STG_A(1, 1, kt3);
        BAR(); LGKM(12); SCHEDB();
        PRIO1(); MFMA8(4, 2, afh, bb1); PRIO0();
        BAR();
    }

    // drain stale prefetches before reusing LDS for the Ucx loop
    VMCNT(0);
    BAR();

    // Ucx prologue: issue now, land under the rg epilogue
    STG_A(0, 0, 0); STG_A(0, 1, 0);
    STG_C(0, 0);
    STG_C(1, 1);

    // ======== rg epilogue: sigmoid(+bias), P cols [1024, 3072) (interleaved r,g) ========
    // inner loop over j -> 4 consecutive 32B chunks per row (write-combining)
    {
        float biasv[4];
#pragma unroll
        for (int j = 0; j < 4; ++j) {
            const int ct = nt * 256 + wn * 64 + j * 16 + r0;
            biasv[j] = (r0 & 1) ? bias_g[ct >> 1] : bias_r[ct >> 1];
        }
#pragma unroll
        for (int i = 0; i < 8; ++i) {
#pragma unroll
            for (int reg = 0; reg < 4; ++reg) {
                const int row = mBase + wm * 128 + i * 16 + gq * 4 + reg;
                __bf16* Pr = (__bf16*)P + (size_t)row * 3072 + 1024 + nt * 256 + wn * 64 + r0;
#pragma unroll
                for (int j = 0; j < 4; ++j) {
                    const float z = 1.0f / (1.0f + __expf(-(acc[i][j][reg] + biasv[j])));
                    Pr[j * 16] = (__bf16)z;
                }
            }
        }
    }

    VMCNT(0);
    BAR();

    // ======== Ucx loop: 256x128, K=1024, 16 K-tiles, 8 iterations x 4 phases ========
#pragma unroll
    for (int i = 0; i < 8; ++i)
#pragma unroll
        for (int j = 0; j < 2; ++j) acc[i][j] = zero;

#pragma unroll 1
    for (int u = 0; u < 8; ++u) {
        const int kt1 = 2 * u + 1;
        const int kt2 = (2 * u + 2) & 15;
        const int kt3 = (2 * u + 3) & 15;

        // P1: tile kt (buf0): issue afl,bu,afh (afh hoisted); stage A(kt+1)->buf1
        LOAD_AF(afl, As[0], rowA);
        LOAD_BF(bb0, Bs[0], rowBu);
        LOAD_AF(afh, As[0], rowA + 64);
        STG_A(1, 0, kt1); STG_A(1, 1, kt1);
        BAR(); LGKM(8); SCHEDB();
        PRIO1(); MFMA8(0, 0, afl, bb0); PRIO0();
        BAR();
        // P2: i4-7; stage C(kt+2)->buf0-B; gate tile kt+1
        STG_C(0, kt2);
        BAR(); LGKM(0); SCHEDB();
        PRIO1(); MFMA8(4, 0, afh, bb0); PRIO0();
        VMCNT(2);
        BAR();
        // P3: tile kt+1 (buf1): issue afl,bu,afh; stage A(kt+2)->buf0-A
        LOAD_AF(afl, As[1], rowA);
        LOAD_BF(bb0, Bs[1], rowBu);
        LOAD_AF(afh, As[1], rowA + 64);
        STG_A(0, 0, kt2); STG_A(0, 1, kt2);
        BAR(); LGKM(8); SCHEDB();
        PRIO1(); MFMA8(0, 0, afl, bb0); PRIO0();
        BAR();
        // P4: i4-7; stage C(kt+3)->buf1-B; gate tile kt+2
        STG_C(1, kt3);
        BAR(); LGKM(0); SCHEDB();
        PRIO1(); MFMA8(4, 0, afh, bb0); PRIO0();
        VMCNT(2);
        BAR();
    }

    // ======== Ucx epilogue: raw bf16, P cols [0, 1024), j-inner for write-combining ========
#pragma unroll
    for (int i = 0; i < 8; ++i) {
#pragma unroll
        for (int reg = 0; reg < 4; ++reg) {
            const int row = mBase + wm * 128 + i * 16 + gq * 4 + reg;
            __bf16* Pr = (__bf16*)P + (size_t)row * 3072 + nt * 128 + wn * 32 + r0;
#pragma unroll
            for (int j = 0; j < 2; ++j)
                Pr[j * 16] = (__bf16)(float)acc[i][j][reg];
        }
    }
    VMCNT(0);
}

#undef STG_A
#undef STG_B
#undef STG_C
#undef LOAD_AF
#undef LOAD_BF
#undef MFMA8

// ---------------- fused butterfly + modReLU + gate ----------------
// Thread t owns cols 4t..4t+3 of 8 rows (all registers).
// Stage H=512: LDS partner t^128; H=256: LDS partner t^64 (3 barriers total).
// Stages H=128..4: __shfl_xor lanemask H/4. Stages H=2,1: in-register permute.
__global__ __launch_bounds__(256) void fuse_kernel(const float* __restrict__ state,
                                                   const __hip_bfloat16* __restrict__ P,
                                                   const float* __restrict__ v1,
                                                   const float* __restrict__ v2,
                                                   const float* __restrict__ bias_c,
                                                   float* __restrict__ out) {
    __shared__ float hbuf[8][1024];
    const int t = threadIdx.x;
    const int rowBase = blockIdx.x * 8;

    float h[8][4];
    float sv[8][4];
#pragma unroll
    for (int r = 0; r < 8; ++r) {
        float4 s4 = ((const float4*)(state + (size_t)(rowBase + r) * 1024))[t];
        h[r][0] = s4.x; h[r][1] = s4.y; h[r][2] = s4.z; h[r][3] = s4.w;
        sv[r][0] = s4.x; sv[r][1] = s4.y; sv[r][2] = s4.z; sv[r][3] = s4.w;
        *(float4*)&hbuf[r][4 * t] = s4;
    }

    // stage 0: H=512, partner thread t^128 (cross-wave -> LDS)
    {
        __syncthreads();
        float4 w1 = *(const float4*)&v1[4 * t];
        float4 w2 = *(const float4*)&v2[4 * (t ^ 128)];
        const float w1v[4] = {w1.x, w1.y, w1.z, w1.w};
        const float w2v[4] = {w2.x, w2.y, w2.z, w2.w};
#pragma unroll
        for (int r = 0; r < 8; ++r) {
            float4 pr = *(const float4*)&hbuf[r][4 * (t ^ 128)];
            const float pv[4] = {pr.x, pr.y, pr.z, pr.w};
#pragma unroll
            for (int e = 0; e < 4; ++e) h[r][e] = h[r][e] * w1v[e] + pv[e] * w2v[e];
        }
        __syncthreads();  // stage-0 reads done before stage-1 writes
    }
    // stage 1: H=256, partner thread t^64 (cross-wave -> LDS)
    {
#pragma unroll
        for (int r = 0; r < 8; ++r)
            *(float4*)&hbuf[r][4 * t] = (float4){h[r][0], h[r][1], h[r][2], h[r][3]};
        __syncthreads();
        float4 w1 = *(const float4*)&v1[1024 + 4 * t];
        float4 w2 = *(const float4*)&v2[1024 + 4 * (t ^ 64)];
        const float w1v[4] = {w1.x, w1.y, w1.z, w1.w};
        const float w2v[4] = {w2.x, w2.y, w2.z, w2.w};
#pragma unroll
        for (int r = 0; r < 8; ++r) {
            float4 pr = *(const float4*)&hbuf[r][4 * (t ^ 64)];
            const float pv[4] = {pr.x, pr.y, pr.z, pr.w};
#pragma unroll
            for (int e = 0; e < 4; ++e) h[r][e] = h[r][e] * w1v[e] + pv[e] * w2v[e];
        }
    }
    // stages 2..7: H=128..4, in-wave shfl_xor with lanemask H/4
#pragma unroll
    for (int i = 2; i <= 7; ++i) {
        const int H = 512 >> i;
        const int lm = H >> 2;  // 32,16,8,4,2,1
        float4 w1 = *(const float4*)&v1[i * 1024 + 4 * t];
        float4 w2 = *(const float4*)&v2[i * 1024 + 4 * (t ^ lm)];
        const float w1v[4] = {w1.x, w1.y, w1.z, w1.w};
        const float w2v[4] = {w2.x, w2.y, w2.z, w2.w};
#pragma unroll
        for (int r = 0; r < 8; ++r) {
#pragma unroll
            for (int e = 0; e < 4; ++e) {
                float p = __shfl_xor(h[r][e], lm, 64);
                h[r][e] = h[r][e] * w1v[e] + p * w2v[e];
            }
        }
    }
    // stage 8: H=2 (element permute e^2); stage 9: H=1 (e^1)
    {
        float4 w1 = *(const float4*)&v1[8 * 1024 + 4 * t];
        float4 w2 = *(const float4*)&v2[8 * 1024 + 4 * t];
        const float w1v[4] = {w1.x, w1.y, w1.z, w1.w};
        const float w2v[4] = {w2.x, w2.y, w2.z, w2.w};
#pragma unroll
        for (int r = 0; r < 8; ++r) {
            float nh[4];
#pragma unroll
            for (int e = 0; e < 4; ++e) nh[e] = h[r][e] * w1v[e] + h[r][e ^ 2] * w2v[e ^ 2];
#pragma unroll
            for (int e = 0; e < 4; ++e) h[r][e] = nh[e];
        }
        float4 u1 = *(const float4*)&v1[9 * 1024 + 4 * t];
        float4 u2 = *(const float4*)&v2[9 * 1024 + 4 * t];
        const float u1v[4] = {u1.x, u1.y, u1.z, u1.w};
        const float u2v[4] = {u2.x, u2.y, u2.z, u2.w};
#pragma unroll
        for (int r = 0; r < 8; ++r) {
            float nh[4];
#pragma unroll
            for (int e = 0; e < 4; ++e) nh[e] = h[r][e] * u1v[e] + h[r][e ^ 1] * u2v[e ^ 1];
#pragma unroll
            for (int e = 0; e < 4; ++e) h[r][e] = nh[e];
        }
    }

    // epilogue: modReLU + gate
    const float4 bc = ((const float4*)bias_c)[t];
    const float bcv[4] = {bc.x, bc.y, bc.z, bc.w};
#pragma unroll
    for (int r = 0; r < 8; ++r) {
        const int row = rowBase + r;
        const __hip_bfloat16* Pr = P + (size_t)row * 3072;
        bf16x4 ux = *(const bf16x4*)((const __bf16*)Pr + 4 * t);        // Ucx, 8 B
        bf16x8 rg = *(const bf16x8*)((const __bf16*)Pr + 1024 + 8 * t); // (r,g) pairs, 16 B
        float o[4];
#pragma unroll
        for (int e = 0; e < 4; ++e) {
            float Ucx = (float)ux[e];
            float rr  = (float)rg[2 * e];
            float gg  = (float)rg[2 * e + 1];
            float pre = rr * h[r][e] + Ucx;
            float mag = fabsf(pre) + 0.001f + bcv[e];
            float c = (pre > 0.f) ? mag : ((pre < 0.f) ? -mag : 0.f);
            o[e] = gg * sv[r][e] + (1.f - gg) * c;
        }
        ((float4*)(out + (size_t)row * 1024))[t] = (float4){o[0], o[1], o[2], o[3]};
    }
}

extern "C" void kernel_launch(void* const* d_in, const int* in_sizes, int n_in,
                              void* d_out, int out_size, void* d_ws, size_t ws_size,
                              hipStream_t stream) {
    const float* x      = (const float*)d_in[0];
    const float* state  = (const float*)d_in[1];
    const float* theta  = (const float*)d_in[2];
    const float* U      = (const float*)d_in[3];
    const float* W_r    = (const float*)d_in[4];
    const float* W_g    = (const float*)d_in[5];
    const float* bias_r = (const float*)d_in[6];
    const float* bias_g = (const float*)d_in[7];
    const float* bias_c = (const float*)d_in[8];
    float* out = (float*)d_out;

    // workspace layout (~90.1 MB)
    __hip_bfloat16* xs   = (__hip_bfloat16*)d_ws;                      // 32 MB
    __hip_bfloat16* Wt0  = xs + (size_t)B_ROWS * 2048;                 // 2 MB
    __hip_bfloat16* Wt12 = Wt0 + (size_t)1024 * 1024;                  // 8 MB (row-interleaved r,g)
    __hip_bfloat16* P    = Wt12 + (size_t)2048 * 2048;                 // 48 MB
    float* v1 = (float*)(P + (size_t)B_ROWS * 3072);                   // 40 KB
    float* v2 = v1 + 10 * 1024;                                        // 40 KB

    prep_all<<<13352, 256, 0, stream>>>(x, state, theta, U, W_r, W_g, xs, Wt0, Wt12, v1, v2);
    gemm_fused<<<256, 512, 0, stream>>>(xs, Wt0, Wt12, bias_r, bias_g, P);
    fuse_kernel<<<1024, 256, 0, stream>>>(state, P, v1, v2, bias_c, out);
}